// Round 9
// baseline (1146.516 us; speedup 1.0000x reference)
//
#include <hip/hip_runtime.h>
#include <hip/hip_bf16.h>
#include <math.h>

typedef __attribute__((ext_vector_type(4))) float f32x4;
typedef __attribute__((ext_vector_type(8))) short bf16x8;

__device__ __forceinline__ unsigned short f2bf(float f) {
  unsigned int x = __builtin_bit_cast(unsigned int, f);
  x += 0x7fffu + ((x >> 16) & 1u);
  return (unsigned short)(x >> 16);
}
__device__ __forceinline__ float bf2f(unsigned short u) {
  unsigned int x = ((unsigned int)u) << 16;
  return __builtin_bit_cast(float, x);
}

__device__ __forceinline__ void gload_lds16(const void* g, void* l) {
  __builtin_amdgcn_global_load_lds(
      (const __attribute__((address_space(1))) unsigned int*)g,
      (__attribute__((address_space(3))) unsigned int*)l, 16, 0, 0);
}

// ---------------- fused f32 -> bf16 weight casts (wq|wp|w1|w2 contiguous) ----------------
__global__ void cvt_all(const float* __restrict__ s0, int n0, const float* __restrict__ s1, int n1,
                        const float* __restrict__ s2, int n2, const float* __restrict__ s3, int n3,
                        unsigned short* __restrict__ d) {
  int i = blockIdx.x * 256 + threadIdx.x;
  if (i >= n0 + n1 + n2 + n3) return;
  const float* s;
  int off;
  if (i < n0) { s = s0; off = 0; }
  else if (i < n0 + n1) { s = s1; off = n0; }
  else if (i < n0 + n1 + n2) { s = s2; off = n0 + n1; }
  else { s = s3; off = n0 + n1 + n2; }
  d[i] = f2bf(s[i - off]);
}

// ---------------- LayerNorm, f32 input (optional shift+window gather) ----------------
template <int REMAP>
__global__ __launch_bounds__(256)
void ln_kernel(const float* __restrict__ x, const float* __restrict__ g,
               const float* __restrict__ b, unsigned short* __restrict__ dst_o) {
  int r = blockIdx.x * 4 + (threadIdx.x >> 6);
  int lane = threadIdx.x & 63;
  size_t src;
  if (REMAP) {
    int w = r >> 6, t = r & 63;
    int bb = w >> 8, wi = (w >> 4) & 15, wj = w & 15;
    int i = t >> 3, j = t & 7;
    int p = (wi * 8 + i + 4) & 127, q = (wj * 8 + j + 4) & 127;
    src = ((size_t)bb * 16384 + p * 128 + q) * 384;
  } else {
    src = (size_t)r * 384;
  }
  float v[6];
  float s = 0.f, s2 = 0.f;
#pragma unroll
  for (int m = 0; m < 6; ++m) {
    v[m] = x[src + lane + 64 * m];
    s += v[m];
    s2 += v[m] * v[m];
  }
#pragma unroll
  for (int o2 = 1; o2 < 64; o2 <<= 1) {
    s += __shfl_xor(s, o2);
    s2 += __shfl_xor(s2, o2);
  }
  float mu = s * (1.f / 384.f);
  float var = s2 * (1.f / 384.f) - mu * mu;
  float ri = rsqrtf(var + 1e-5f);
  size_t dst = (size_t)r * 384;
#pragma unroll
  for (int m = 0; m < 6; ++m) {
    int c = lane + 64 * m;
    dst_o[dst + c] = f2bf((v[m] - mu) * ri * g[c] + b[c]);
  }
}

// ---------------- LayerNorm, bf16 input ----------------
__global__ __launch_bounds__(256)
void ln_bf16(const unsigned short* __restrict__ x, const float* __restrict__ g,
             const float* __restrict__ b, unsigned short* __restrict__ dst_o) {
  int r = blockIdx.x * 4 + (threadIdx.x >> 6);
  int lane = threadIdx.x & 63;
  size_t src = (size_t)r * 384;
  float v[6];
  float s = 0.f, s2 = 0.f;
#pragma unroll
  for (int m = 0; m < 3; ++m) {
    unsigned int u = *(const unsigned int*)&x[src + lane * 2 + 128 * m];
    v[2 * m] = bf2f((unsigned short)(u & 0xffffu));
    v[2 * m + 1] = bf2f((unsigned short)(u >> 16));
    s += v[2 * m] + v[2 * m + 1];
    s2 += v[2 * m] * v[2 * m] + v[2 * m + 1] * v[2 * m + 1];
  }
#pragma unroll
  for (int o2 = 1; o2 < 64; o2 <<= 1) {
    s += __shfl_xor(s, o2);
    s2 += __shfl_xor(s2, o2);
  }
  float mu = s * (1.f / 384.f);
  float var = s2 * (1.f / 384.f) - mu * mu;
  float ri = rsqrtf(var + 1e-5f);
#pragma unroll
  for (int m = 0; m < 3; ++m) {
    int c = lane * 2 + 128 * m;
    unsigned int lo = f2bf((v[2 * m] - mu) * ri * g[c] + b[c]);
    unsigned int hi = f2bf((v[2 * m + 1] - mu) * ri * g[c + 1] + b[c + 1]);
    *(unsigned int*)&dst_o[src + c] = lo | (hi << 16);
  }
}

// ---------------- GEMM: C(M,N) = A(M,K) * B(N,K)^T ----------------
// BM=256, BN=192 (all Ns divide 192), BK=64. 512 thr / 8 waves (4M x 2N),
// wave tile 64x96: per kk 10 ds_read -> 24 MFMA. 2-buf LDS (112KB).
// PROLOGUE: stage(0); vmcnt(0); barrier   <-- the R8 bug was dropping this;
//   tile(0)'s ds_reads raced the in-flight global_load_lds writes of stage(0).
// Per K-tile: stage(t+1) first, then two phases
//   { 10 ds_read ; s_barrier ; setprio(1) ; 24 MFMA ; setprio(0) ; s_barrier }
// then vmcnt(0)+barrier (stage(t+1) had the whole tile to land). t+=2 unroll
// gives static buffer pointers. T2 both-sides swizzle (0 conflicts, verified
// R4). Bijective XCD swizzle (m204).
// EPI 0: bf16(acc+bias) | 1: bf16(gelu) | 2: proj scatter+resid->bf16 | 3: f32+resid
template <int EPI>
__global__ __launch_bounds__(512, 1)
void gemm9(const unsigned short* __restrict__ A, const unsigned short* __restrict__ Bw,
           const float* __restrict__ bias, int M, int N, int K, int NT,
           unsigned short* __restrict__ Obf, const void* __restrict__ resid,
           float* __restrict__ Of) {
  extern __shared__ unsigned short lds[];  // 2 x (A 256x64 + B 192x64) ushorts
  const int tid = threadIdx.x;
  const int lane = tid & 63;
  const int wid = tid >> 6;               // 0..7
  const int wm = wid >> 1, wn = wid & 1;  // wave grid 4M x 2N, wave tile 64x96
  const int li = lane & 15, lg = lane >> 4;

  // bijective XCD swizzle (m204)
  const int nwg = gridDim.x;
  const int orig = blockIdx.x;
  const int q = nwg >> 3, r = nwg & 7;
  const int xcd = orig & 7, loc = orig >> 3;
  const int wg = (xcd < r ? xcd * (q + 1) : r * (q + 1) + (xcd - r) * q) + loc;
  const int m0 = (wg / NT) * 256;
  const int n0 = (wg % NT) * 192;

  // staging: per round 512 thr x 16B = 64 rows x 128B; A 4 rounds, B 3 rounds.
  // linear LDS dest; inverse-swizzled global source col (row&7 == lane>>3).
  const int srow = wid * 8 + (lane >> 3);
  const int scol = ((lane & 7) ^ (lane >> 3)) * 8;
  const unsigned short* gA = A + (size_t)(m0 + srow) * K + scol;
  const unsigned short* gB = Bw + (size_t)(n0 + srow) * K + scol;

  const int nk = K >> 6;
  const int fswz = (li & 7) << 3;  // read-side swizzle (frag row&7 == li&7)
  f32x4 acc[4][6] = {};

  auto stage = [&](int k, unsigned short* dst) {
    unsigned short* dB = dst + 16384;
#pragma unroll
    for (int c = 0; c < 4; ++c)
      gload_lds16(gA + (size_t)(c * 64) * K + k * 64, &dst[c * 4096 + wid * 512]);
#pragma unroll
    for (int c = 0; c < 3; ++c)
      gload_lds16(gB + (size_t)(c * 64) * K + k * 64, &dB[c * 4096 + wid * 512]);
  };

  unsigned short* const buf0 = lds;
  unsigned short* const buf1 = lds + 28672;

  auto tile = [&](int t, unsigned short* cur, unsigned short* nxt) {
    if (t + 1 < nk) stage(t + 1, nxt);  // issue stage FIRST (T3 recipe)
    const unsigned short* pA = cur;
    const unsigned short* pB = cur + 16384;
#pragma unroll
    for (int kk = 0; kk < 2; ++kk) {
      bf16x8 a[4], b[6];
#pragma unroll
      for (int f = 0; f < 4; ++f)
        a[f] = *(const bf16x8*)&pA[(wm * 64 + f * 16 + li) * 64 + ((kk * 32 + lg * 8) ^ fswz)];
#pragma unroll
      for (int f = 0; f < 6; ++f)
        b[f] = *(const bf16x8*)&pB[(wn * 96 + f * 16 + li) * 64 + ((kk * 32 + lg * 8) ^ fswz)];
      __builtin_amdgcn_s_barrier();
      __builtin_amdgcn_s_setprio(1);
#pragma unroll
      for (int mf = 0; mf < 4; ++mf)
#pragma unroll
        for (int nf = 0; nf < 6; ++nf)
          acc[mf][nf] = __builtin_amdgcn_mfma_f32_16x16x32_bf16(a[mf], b[nf], acc[mf][nf], 0, 0, 0);
      __builtin_amdgcn_s_setprio(0);
      if (kk == 0) __builtin_amdgcn_s_barrier();
    }
    asm volatile("s_waitcnt vmcnt(0)" ::: "memory");  // nxt fully landed
    __builtin_amdgcn_s_barrier();
  };

  // prologue: stage K-tile 0 and DRAIN before first ds_read (fixes R8 race)
  stage(0, buf0);
  asm volatile("s_waitcnt vmcnt(0)" ::: "memory");
  __builtin_amdgcn_s_barrier();

  for (int t = 0; t < nk; t += 2) {  // nk is even (6 or 24); buffers static
    tile(t, buf0, buf1);
    tile(t + 1, buf1, buf0);
  }

  // epilogue: C/D layout col = lane&15, row = (lane>>4)*4 + reg
#pragma unroll
  for (int mf = 0; mf < 4; ++mf) {
#pragma unroll
    for (int r2 = 0; r2 < 4; ++r2) {
      int mrow = m0 + wm * 64 + mf * 16 + lg * 4 + r2;
      size_t orow = (size_t)mrow;
      if (EPI == 2) {
        int w = mrow >> 6, t = mrow & 63;
        int bb2 = w >> 8, wi = (w >> 4) & 15, wj = w & 15;
        int i = t >> 3, j = t & 7;
        int p = (wi * 8 + i + 4) & 127, qq = (wj * 8 + j + 4) & 127;
        orow = (size_t)bb2 * 16384 + p * 128 + qq;
      }
#pragma unroll
      for (int nf = 0; nf < 6; ++nf) {
        int col = n0 + wn * 96 + nf * 16 + li;
        float v = acc[mf][nf][r2] + bias[col];
        if (EPI == 0) {
          Obf[(size_t)mrow * N + col] = f2bf(v);
        } else if (EPI == 1) {
          float y = 1.5957691f * (v + 0.044715f * v * v * v);
          float gl = v * __builtin_amdgcn_rcpf(1.f + __expf(-y));
          Obf[(size_t)mrow * N + col] = f2bf(gl);
        } else if (EPI == 2) {
          const float* rx = (const float*)resid;
          Obf[orow * 384 + col] = f2bf(v + rx[orow * 384 + col]);
        } else {
          const unsigned short* rx = (const unsigned short*)resid;
          Of[(size_t)mrow * N + col] = v + bf2f(rx[(size_t)mrow * N + col]);
        }
      }
    }
  }
}

// ---------------- windowed attention: block = (window, head-triple); 4 waves ----------------
__global__ __launch_bounds__(256, 2)
void attn_kernel(const unsigned short* __restrict__ qkv, const float* __restrict__ btab,
                 const float* __restrict__ mask, unsigned short* __restrict__ out) {
  __shared__ unsigned short v_lds[4][64 * 40];  // V tile, row stride 40
  __shared__ unsigned short p_lds[4][64 * 72];  // P tile, row stride 72
  const int w = blockIdx.x;
  const int hi = blockIdx.y;  // 0..2
  const int tid = threadIdx.x;
  const int wid = tid >> 6, lane = tid & 63;
  const int li = lane & 15, lg = lane >> 4;
  const float* mrow = mask + (size_t)(w & 255) * 4096;
  const size_t base = (size_t)w * 64;
  const float SC = 0.17677669529663688f;  // 32^-0.5

  int h = wid * 3 + hi;
  bf16x8 aq[4], bk[4];
#pragma unroll
  for (int f = 0; f < 4; ++f) {
    size_t off = (base + f * 16 + li) * 1152 + h * 32 + lg * 8;
    aq[f] = *(const bf16x8*)&qkv[off];
    bk[f] = *(const bf16x8*)&qkv[off + 384];
  }
  f32x4 s[4][4] = {};
#pragma unroll
  for (int mf = 0; mf < 4; ++mf)
#pragma unroll
    for (int nf = 0; nf < 4; ++nf)
      s[mf][nf] = __builtin_amdgcn_mfma_f32_16x16x32_bf16(aq[mf], bk[nf], s[mf][nf], 0, 0, 0);

  {
    const unsigned short* vp = &qkv[(base + lane) * 1152 + 768 + h * 32];
    unsigned short* dp = &v_lds[wid][lane * 40];
#pragma unroll
    for (int c = 0; c < 4; ++c) *(bf16x8*)&dp[c * 8] = *(const bf16x8*)&vp[c * 8];
  }

#pragma unroll
  for (int mf = 0; mf < 4; ++mf) {
#pragma unroll
    for (int r = 0; r < 4; ++r) {
      int m = mf * 16 + lg * 4 + r;
      float mx = -1e30f;
#pragma unroll
      for (int nf = 0; nf < 4; ++nf) {
        int n = nf * 16 + li;
        int ridx = ((m >> 3) - (n >> 3) + 7) * 15 + (m & 7) - (n & 7) + 7;
        float val = s[mf][nf][r] * SC + btab[ridx * 12 + h] + mrow[m * 64 + n];
        s[mf][nf][r] = val;
        mx = fmaxf(mx, val);
      }
#pragma unroll
      for (int o2 = 1; o2 < 16; o2 <<= 1) mx = fmaxf(mx, __shfl_xor(mx, o2));
      float sum = 0.f;
#pragma unroll
      for (int nf = 0; nf < 4; ++nf) {
        float e = __expf(s[mf][nf][r] - mx);
        s[mf][nf][r] = e;
        sum += e;
      }
#pragma unroll
      for (int o2 = 1; o2 < 16; o2 <<= 1) sum += __shfl_xor(sum, o2);
      float inv = __builtin_amdgcn_rcpf(sum);
#pragma unroll
      for (int nf = 0; nf < 4; ++nf) s[mf][nf][r] *= inv;
    }
  }

#pragma unroll
  for (int mf = 0; mf < 4; ++mf)
#pragma unroll
    for (int nf = 0; nf < 4; ++nf)
#pragma unroll
      for (int r = 0; r < 4; ++r) {
        int m = mf * 16 + lg * 4 + r, n = nf * 16 + li;
        p_lds[wid][m * 72 + n] = f2bf(s[mf][nf][r]);
      }

  f32x4 o[4][2] = {};
#pragma unroll
  for (int kf = 0; kf < 2; ++kf) {
    bf16x8 bv[2];
#pragma unroll
    for (int df = 0; df < 2; ++df) {
      bf16x8 t;
#pragma unroll
      for (int e = 0; e < 8; ++e)
        t[e] = (short)v_lds[wid][(kf * 32 + lg * 8 + e) * 40 + df * 16 + li];
      bv[df] = t;
    }
#pragma unroll
    for (int mf = 0; mf < 4; ++mf) {
      bf16x8 pa = *(const bf16x8*)&p_lds[wid][(mf * 16 + li) * 72 + kf * 32 + lg * 8];
#pragma unroll
      for (int df = 0; df < 2; ++df)
        o[mf][df] = __builtin_amdgcn_mfma_f32_16x16x32_bf16(pa, bv[df], o[mf][df], 0, 0, 0);
    }
  }

#pragma unroll
  for (int mf = 0; mf < 4; ++mf)
#pragma unroll
    for (int df = 0; df < 2; ++df)
#pragma unroll
      for (int r = 0; r < 4; ++r) {
        size_t row = base + mf * 16 + lg * 4 + r;
        out[row * 384 + h * 32 + df * 16 + li] = f2bf(o[mf][df][r]);
      }
}

extern "C" void kernel_launch(void* const* d_in, const int* in_sizes, int n_in,
                              void* d_out, int out_size, void* d_ws, size_t ws_size,
                              hipStream_t stream) {
  const float* x      = (const float*)d_in[0];
  const float* qkv_w  = (const float*)d_in[1];
  const float* qkv_b  = (const float*)d_in[2];
  const float* proj_w = (const float*)d_in[3];
  const float* proj_b = (const float*)d_in[4];
  const float* rel    = (const float*)d_in[5];
  const float* g1     = (const float*)d_in[6];
  const float* b1     = (const float*)d_in[7];
  const float* g2     = (const float*)d_in[8];
  const float* b2     = (const float*)d_in[9];
  const float* fc1_w  = (const float*)d_in[10];
  const float* fc1_b  = (const float*)d_in[11];
  const float* fc2_w  = (const float*)d_in[12];
  const float* fc2_b  = (const float*)d_in[13];
  const float* mask   = (const float*)d_in[14];
  float* out = (float*)d_out;
  char* ws = (char*)d_ws;

  const int M = 131072;  // B * H * W tokens
  const int LDS_BYTES = 2 * 57344;  // 112 KB, 2-buf (A 256x64 + B 192x64)
  (void)hipFuncSetAttribute((const void*)gemm9<0>, hipFuncAttributeMaxDynamicSharedMemorySize, LDS_BYTES);
  (void)hipFuncSetAttribute((const void*)gemm9<1>, hipFuncAttributeMaxDynamicSharedMemorySize, LDS_BYTES);
  (void)hipFuncSetAttribute((const void*)gemm9<2>, hipFuncAttributeMaxDynamicSharedMemorySize, LDS_BYTES);
  (void)hipFuncSetAttribute((const void*)gemm9<3>, hipFuncAttributeMaxDynamicSharedMemorySize, LDS_BYTES);

  unsigned short* hw     = (unsigned short*)ws;
  unsigned short* qkv    = (unsigned short*)(ws + 100663296);
  unsigned short* hmid   = (unsigned short*)ws;
  unsigned short* attn_o = (unsigned short*)(ws + 402653184);
  unsigned short* ln2o   = attn_o;
  unsigned short* x1b    = (unsigned short*)(ws + 503316480);
  unsigned short* wq     = (unsigned short*)(ws + 603979776);
  unsigned short* wp     = wq + 442368;
  unsigned short* w1     = wp + 147456;
  unsigned short* w2     = w1 + 589824;

  // fused weight casts (wq|wp|w1|w2 are contiguous)
  cvt_all<<<(442368 + 147456 + 589824 + 589824 + 255) / 256, 256, 0, stream>>>(
      qkv_w, 442368, proj_w, 147456, fc1_w, 589824, fc2_w, 589824, wq);

  // LN1 + shift + window partition
  ln_kernel<1><<<M / 4, 256, 0, stream>>>(x, g1, b1, hw);

  // QKV projection: grid (M/256)*(1152/192) = 512*6
  gemm9<0><<<512 * 6, 512, LDS_BYTES, stream>>>(hw, wq, qkv_b, M, 1152, 384, 6, qkv, nullptr, nullptr);

  // windowed attention (one head-triple per block.y)
  attn_kernel<<<dim3(2048, 3), 256, 0, stream>>>(qkv, rel, mask, attn_o);

  // proj + window reverse + unshift + residual(x f32) -> x1 (bf16): 512*2
  gemm9<2><<<512 * 2, 512, LDS_BYTES, stream>>>(attn_o, wp, proj_b, M, 384, 384, 2, x1b, x, nullptr);

  // LN2 (bf16 in)
  ln_bf16<<<M / 4, 256, 0, stream>>>(x1b, g2, b2, ln2o);

  // FC1 + GELU: 512*8
  gemm9<1><<<512 * 8, 512, LDS_BYTES, stream>>>(ln2o, w1, fc1_b, M, 1536, 384, 8, hmid, nullptr, nullptr);

  // FC2 + residual(x1 bf16) -> out (f32): 512*2
  gemm9<3><<<512 * 2, 512, LDS_BYTES, stream>>>(hmid, w2, fc2_b, M, 384, 1536, 2, nullptr, x1b, out);
}